// Round 1
// baseline (783.253 us; speedup 1.0000x reference)
//
#include <hip/hip_runtime.h>
#include <hip/hip_bf16.h>

// B=4, S=2048, D=1024, H=16, HD=64. Inputs/output bf16 (flag=1 proven rounds 5+9).
// ws total 29.36 MB (passes observed up to 33.6MB; NaN only >56MB).
// ROUND 11 DELTA vs round 10 (attn_mfma, unverified due to container failure):
//   1. attn V^T staging: column-gather + vector ds_write (was 16-way bank-conflict scatter)
//   2. attn: post-Ps __syncthreads removed (Ps is wave-private) -> lgkmcnt(0)+sched_barrier
//   3. attn: heavy q-tiles launch first (causal load balance)
//   4. output GEMM pair-batched: M=4096, grid 256 blocks, 2 launches (was 4x128 blocks)

typedef float f32x4 __attribute__((ext_vector_type(4)));
typedef short bf16x8 __attribute__((ext_vector_type(8)));

__device__ __forceinline__ ushort f2b(float f) {
  unsigned int x = __float_as_uint(f);
  unsigned int r = (x + 0x7fffu + ((x >> 16) & 1u)) >> 16;  // RNE
  return (ushort)r;
}
__device__ __forceinline__ float b2f(ushort u) {
  return __uint_as_float(((unsigned int)u) << 16);
}

// ---------------- dtype detector (insurance; proven round 5/9) ----------------
__global__ void detect_dtype(const unsigned int* __restrict__ x, int* __restrict__ flag) {
  __shared__ int cnt;
  if (threadIdx.x == 0) cnt = 0;
  __syncthreads();
  unsigned int w = x[threadIdx.x];
  int e = (w >> 7) & 0xff;
  atomicAdd(&cnt, (e >= 96 && e <= 160) ? 1 : 0);
  __syncthreads();
  if (threadIdx.x == 0) flag[0] = (cnt >= 614) ? 1 : 0;
}

// ---------------- transpose: in (dtype per flag) [K][N] -> out bf16 [N][K] ----------------
__global__ void transpose_any(const void* __restrict__ in, ushort* __restrict__ out,
                              int K, int N, const int* __restrict__ flag) {
  __shared__ ushort tile[64][65];
  int bf = flag[0];
  int k0 = blockIdx.y * 64, n0 = blockIdx.x * 64;
  int t = threadIdx.x;  // 256
#pragma unroll
  for (int i = 0; i < 16; ++i) {
    int idx = i * 256 + t;
    int r = idx >> 6, c = idx & 63;
    size_t g = (size_t)(k0 + r) * N + (n0 + c);
    tile[r][c] = bf ? ((const ushort*)in)[g] : f2b(((const float*)in)[g]);
  }
  __syncthreads();
#pragma unroll
  for (int i = 0; i < 16; ++i) {
    int idx = i * 256 + t;
    int r = idx >> 6, c = idx & 63;
    out[(size_t)(n0 + r) * K + (k0 + c)] = tile[c][r];
  }
}

// ---------------- MFMA GEMM: C[M,N] = A[M,K] @ BT[N,K]^T + bias (round 9, proven) ----------------
#define BM 128
#define BN 128
#define BKK 32
#define LDA 40  // padded LDS row stride (elements); 80B, 16B-aligned

__global__ void gemm_bt(const void* __restrict__ A, const ushort* __restrict__ BT,
                        const void* __restrict__ bias, void* __restrict__ C,
                        int M, int N, int K, size_t a_off, size_t c_off,
                        const int* __restrict__ flag, int a_is_input, int c_is_output) {
  __shared__ __align__(16) ushort As[BM * LDA];
  __shared__ __align__(16) ushort Bs[BN * LDA];
  int bf = flag[0];
  int a_bf = a_is_input ? bf : 1;
  int tid = threadIdx.x;
  int wave = tid >> 6, lane = tid & 63;
  int lrow = lane & 15, quad = lane >> 4;
  int m0 = blockIdx.y * BM, n0 = blockIdx.x * BN;
  int wm = (wave >> 1) * 64, wn = (wave & 1) * 64;

  f32x4 acc[4][4] = {};

  const ushort* Bp = BT + (size_t)n0 * K;

  for (int kt = 0; kt < K; kt += BKK) {
    uint4 av[2], bv[2];
#pragma unroll
    for (int j = 0; j < 2; ++j) {
      int idx = j * 256 + tid;
      int r = idx >> 2;
      int c = (idx & 3) << 3;
      size_t ga = a_off + (size_t)(m0 + r) * K + kt + c;
      if (a_bf) {
        av[j] = *(const uint4*)((const ushort*)A + ga);
      } else {
        const float* Af = (const float*)A + ga;
        float4 f0 = *(const float4*)Af;
        float4 f1 = *(const float4*)(Af + 4);
        ushort tmp[8] = {f2b(f0.x), f2b(f0.y), f2b(f0.z), f2b(f0.w),
                         f2b(f1.x), f2b(f1.y), f2b(f1.z), f2b(f1.w)};
        av[j] = *(const uint4*)tmp;
      }
      bv[j] = *(const uint4*)(Bp + (size_t)r * K + kt + c);
    }
    __syncthreads();
#pragma unroll
    for (int j = 0; j < 2; ++j) {
      int idx = j * 256 + tid;
      int r = idx >> 2;
      int c = (idx & 3) << 3;
      *(uint4*)&As[r * LDA + c] = av[j];
      *(uint4*)&Bs[r * LDA + c] = bv[j];
    }
    __syncthreads();

    bf16x8 af[4], bfr[4];
#pragma unroll
    for (int i = 0; i < 4; ++i) {
      af[i] = *(const bf16x8*)&As[(wm + i * 16 + lrow) * LDA + quad * 8];
      bfr[i] = *(const bf16x8*)&Bs[(wn + i * 16 + lrow) * LDA + quad * 8];
    }
#pragma unroll
    for (int i = 0; i < 4; ++i)
#pragma unroll
      for (int j = 0; j < 4; ++j)
        acc[i][j] = __builtin_amdgcn_mfma_f32_16x16x32_bf16(af[i], bfr[j], acc[i][j], 0, 0, 0);
  }

#pragma unroll
  for (int i = 0; i < 4; ++i) {
#pragma unroll
    for (int j = 0; j < 4; ++j) {
      int colg = n0 + wn + j * 16 + lrow;
      float bvs = bf ? b2f(((const ushort*)bias)[colg]) : ((const float*)bias)[colg];
#pragma unroll
      for (int r = 0; r < 4; ++r) {
        int rowg = m0 + wm + i * 16 + quad * 4 + r;
        float val = acc[i][j][r] + bvs;
        size_t ci = c_off + (size_t)rowg * N + colg;
        if (c_is_output && !bf)
          ((float*)C)[ci] = val;
        else
          ((ushort*)C)[ci] = f2b(val);
      }
    }
  }
}

// ---------------- MFMA causal flash attention (one batch) ----------------
// qkv [2048][3072] bf16: row = [Q 0..1023 | K 1024..2047 | V 2048..3071], head h at h*64.
// attn [2048][1024] bf16 output.
// grid (32, 16): q-tile = 31 - blockIdx.x (heavy first), blockIdx.y = h. block 256 (4 waves x 16 q).
#define LDK 72  // 144B row stride, 16B-aligned

__global__ void attn_mfma(const ushort* __restrict__ qkv, ushort* __restrict__ attn) {
  __shared__ __align__(16) ushort Ks[64 * LDK];   // [key][hd]
  __shared__ __align__(16) ushort Vs[64 * LDK];   // [hd][key] (transposed at stage)
  __shared__ __align__(16) ushort Ps[4][16 * LDK];

  int h = blockIdx.y;
  int qt = gridDim.x - 1 - blockIdx.x;  // heavy tiles dispatch first
  int q0 = qt * 64;
  int tid = threadIdx.x, wave = tid >> 6, lane = tid & 63;
  int lrow = lane & 15, quad = lane >> 4;

  // Q fragments for this wave's 16 rows: A[m=lrow][k=quad*8+j]
  bf16x8 qa[2];
#pragma unroll
  for (int kk = 0; kk < 2; ++kk)
    qa[kk] = *(const bf16x8*)(qkv + (size_t)(q0 + wave * 16 + lrow) * 3072 +
                              h * 64 + kk * 32 + quad * 8);

  f32x4 o[4] = {};
  float mi[4], li[4];
#pragma unroll
  for (int r = 0; r < 4; ++r) { mi[r] = -1e30f; li[r] = 0.f; }
  int row_g_base = q0 + wave * 16 + quad * 4;

  int ntiles = qt + 1;  // causal: keys [0, q0+64)
  for (int kt = 0; kt < ntiles; ++kt) {
    __syncthreads();  // previous iteration's Ks/Vs reads done
#pragma unroll
    for (int j = 0; j < 2; ++j) {
      int idx = j * 256 + tid;
      {  // K tile, row-vector copy (conflict-free)
        int r = idx >> 3;
        int c = (idx & 7) << 3;
        *(uint4*)&Ks[r * LDK + c] =
            *(const uint4*)(qkv + (size_t)(kt * 64 + r) * 3072 + 1024 + h * 64 + c);
      }
      {  // V tile transposed: per-thread column gather (per-wave 128B-coalesced rows),
         // single contiguous uint4 ds_write -> no bank conflicts
        int hd = idx & 63;   // == lane within each wave
        int kb = idx >> 6;   // key block 0..7, uniform per wave
        const ushort* vg = qkv + (size_t)(kt * 64 + kb * 8) * 3072 + 2048 + h * 64 + hd;
        __align__(16) ushort col[8];
#pragma unroll
        for (int e = 0; e < 8; ++e) col[e] = vg[(size_t)e * 3072];
        *(uint4*)&Vs[hd * LDK + kb * 8] = *(const uint4*)col;
      }
    }
    __syncthreads();

    // S = Q K^T (16 q-rows x 64 keys), C-layout (col=lrow=key, row=quad*4+r=q)
    f32x4 s4[4];
#pragma unroll
    for (int t = 0; t < 4; ++t) {
      f32x4 a = {};
#pragma unroll
      for (int kk = 0; kk < 2; ++kk) {
        bf16x8 kb = *(const bf16x8*)&Ks[(t * 16 + lrow) * LDK + kk * 32 + quad * 8];
        a = __builtin_amdgcn_mfma_f32_16x16x32_bf16(qa[kk], kb, a, 0, 0, 0);
      }
      s4[t] = a;
    }

    float tmax[4];
#pragma unroll
    for (int r = 0; r < 4; ++r) tmax[r] = -1e30f;
#pragma unroll
    for (int t = 0; t < 4; ++t) {
      int colg = kt * 64 + t * 16 + lrow;
#pragma unroll
      for (int r = 0; r < 4; ++r) {
        float v = s4[t][r] * 0.125f;
        if (colg > row_g_base + r) v = -1e30f;
        s4[t][r] = v;
        tmax[r] = fmaxf(tmax[r], v);
      }
    }
#pragma unroll
    for (int off = 8; off >= 1; off >>= 1)
#pragma unroll
      for (int r = 0; r < 4; ++r)
        tmax[r] = fmaxf(tmax[r], __shfl_xor(tmax[r], off, 64));

    float al[4], ps[4];
#pragma unroll
    for (int r = 0; r < 4; ++r) {
      float nm = fmaxf(mi[r], tmax[r]);
      al[r] = __expf(mi[r] - nm);
      mi[r] = nm;
      ps[r] = 0.f;
    }
#pragma unroll
    for (int t = 0; t < 4; ++t)
#pragma unroll
      for (int r = 0; r < 4; ++r) {
        float p = __expf(s4[t][r] - mi[r]);
        s4[t][r] = p;
        ps[r] += p;
      }
#pragma unroll
    for (int off = 8; off >= 1; off >>= 1)
#pragma unroll
      for (int r = 0; r < 4; ++r) ps[r] += __shfl_xor(ps[r], off, 64);
#pragma unroll
    for (int r = 0; r < 4; ++r) li[r] = li[r] * al[r] + ps[r];
#pragma unroll
    for (int t = 0; t < 4; ++t)
#pragma unroll
      for (int r = 0; r < 4; ++r) o[t][r] *= al[r];

    // P: C-layout -> LDS (wave-private) -> A-layout. No block barrier needed:
    // Ps[wave] is only touched by this wave; order via lgkmcnt + sched fence (rule 18).
#pragma unroll
    for (int t = 0; t < 4; ++t)
#pragma unroll
      for (int r = 0; r < 4; ++r)
        Ps[wave][(quad * 4 + r) * LDK + t * 16 + lrow] = f2b(s4[t][r]);

    asm volatile("s_waitcnt lgkmcnt(0)" ::: "memory");
    __builtin_amdgcn_sched_barrier(0);

    bf16x8 pa[2];
#pragma unroll
    for (int kk = 0; kk < 2; ++kk)
      pa[kk] = *(const bf16x8*)&Ps[wave][lrow * LDK + kk * 32 + quad * 8];
#pragma unroll
    for (int t = 0; t < 4; ++t)
#pragma unroll
      for (int kk = 0; kk < 2; ++kk) {
        bf16x8 vb = *(const bf16x8*)&Vs[(t * 16 + lrow) * LDK + kk * 32 + quad * 8];
        o[t] = __builtin_amdgcn_mfma_f32_16x16x32_bf16(pa[kk], vb, o[t], 0, 0, 0);
      }
  }

  // normalize + store attn[q][h*64 + t*16+lrow]
#pragma unroll
  for (int r = 0; r < 4; ++r) {
    float inv = 1.f / li[r];
    int q = q0 + wave * 16 + quad * 4 + r;
    size_t base = (size_t)q * 1024 + h * 64;
#pragma unroll
    for (int t = 0; t < 4; ++t) attn[base + t * 16 + lrow] = f2b(o[t][r] * inv);
  }
}

static const void* ptr_by_size(void* const* d_in, const int* in_sizes, int n_in,
                               int want, int fallback_idx) {
  for (int i = 0; i < n_in; ++i)
    if (in_sizes[i] == want) return d_in[i];
  return d_in[fallback_idx];
}

extern "C" void kernel_launch(void* const* d_in, const int* in_sizes, int n_in,
                              void* d_out, int out_size, void* d_ws, size_t ws_size,
                              hipStream_t stream) {
  const void* x    = ptr_by_size(d_in, in_sizes, n_in, 8388608, 0);  // [4,2048,1024]
  const void* Wqkv = ptr_by_size(d_in, in_sizes, n_in, 3145728, 1);  // [1024,3072]
  const void* bqkv = ptr_by_size(d_in, in_sizes, n_in, 3072,    2);  // [3072]
  const void* Wout = ptr_by_size(d_in, in_sizes, n_in, 1048576, 3);  // [1024,1024]
  const void* bout = ptr_by_size(d_in, in_sizes, n_in, 1024,    4);  // [1024]

  char* ws = (char*)d_ws;
  int*    flag  = (int*)ws;                        // 256 B
  ushort* WT1   = (ushort*)(ws + 256);             // [3072][1024] bf16  6.29 MB
  ushort* WT2   = (ushort*)(ws + 256 + 6291456);   // [1024][1024] bf16  2.10 MB
  ushort* qkvb  = (ushort*)(ws + 256 + 8388608);   // [2048][3072] bf16 12.58 MB
  ushort* attnb = (ushort*)(ws + 256 + 20971520);  // 2x [2048][1024] bf16  8.39 MB
  // total ~29.36 MB (observed-passing band is <= 33.6 MB)

  detect_dtype<<<1, 1024, 0, stream>>>((const unsigned int*)x, flag);
  transpose_any<<<dim3(48, 16), 256, 0, stream>>>(Wqkv, WT1, 1024, 3072, flag);
  transpose_any<<<dim3(16, 16), 256, 0, stream>>>(Wout, WT2, 1024, 1024, flag);

  for (int p = 0; p < 2; ++p) {
    for (int bb = 0; bb < 2; ++bb) {
      int b = p * 2 + bb;
      gemm_bt<<<dim3(24, 16), 256, 0, stream>>>(
          x, WT1, bqkv, qkvb, 2048, 3072, 1024,
          (size_t)b * 2048 * 1024, 0, flag, /*a_is_input=*/1, /*c_is_output=*/0);
      attn_mfma<<<dim3(32, 16), 256, 0, stream>>>(qkvb, attnb + (size_t)bb * 2048 * 1024);
    }
    // pair-batched output projection: M=4096 -> 256 blocks (fills the 256-CU chip)
    gemm_bt<<<dim3(8, 32), 256, 0, stream>>>(
        attnb, WT2, bout, d_out, 4096, 1024, 1024,
        0, (size_t)p * 4096 * 1024, flag, /*a_is_input=*/0, /*c_is_output=*/1);
  }
}

// Round 2
// 748.381 us; speedup vs baseline: 1.0466x; 1.0466x over previous
//
#include <hip/hip_runtime.h>
#include <hip/hip_bf16.h>

// B=4, S=2048, D=1024, H=16, HD=64. Inputs/output bf16 (flag=1 proven rounds 5+9+11).
// ws total 33,554,688 B == the largest previously observed PASSING ws (33.6MB). NaN only >56MB.
// ROUND 12 DELTA vs green round 11 (783 us; QKV gemm occupancy-bound at 16%):
//   1. QKV GEMM pair-batched: M=4096, grid (24,32)=768 blocks (was 384), 2 launches
//   2. attn batched over pair: grid (32,16,2)=1024 blocks; OUTPUT WRITTEN INTO Q REGION
//      of qkvb (Q is register-resident per block before any write; no cross-block Q reads)
//      -> attnb buffer eliminated, qkvb can hold 2 batches
//   3. gemm_bt + attn_mfma: register-prefetch software pipeline (next tile's global loads
//      issued after the 2nd barrier, latency hidden under MFMA/softmax of current tile)
//   4. gemm_bt gains lda param (out-proj reads A from qkvb Q region, row stride 3072)

typedef float f32x4 __attribute__((ext_vector_type(4)));
typedef short bf16x8 __attribute__((ext_vector_type(8)));

__device__ __forceinline__ ushort f2b(float f) {
  unsigned int x = __float_as_uint(f);
  unsigned int r = (x + 0x7fffu + ((x >> 16) & 1u)) >> 16;  // RNE
  return (ushort)r;
}
__device__ __forceinline__ float b2f(ushort u) {
  return __uint_as_float(((unsigned int)u) << 16);
}

// ---------------- dtype detector (insurance; proven round 5/9) ----------------
__global__ void detect_dtype(const unsigned int* __restrict__ x, int* __restrict__ flag) {
  __shared__ int cnt;
  if (threadIdx.x == 0) cnt = 0;
  __syncthreads();
  unsigned int w = x[threadIdx.x];
  int e = (w >> 7) & 0xff;
  atomicAdd(&cnt, (e >= 96 && e <= 160) ? 1 : 0);
  __syncthreads();
  if (threadIdx.x == 0) flag[0] = (cnt >= 614) ? 1 : 0;
}

// ---------------- transpose: in (dtype per flag) [K][N] -> out bf16 [N][K] ----------------
__global__ void transpose_any(const void* __restrict__ in, ushort* __restrict__ out,
                              int K, int N, const int* __restrict__ flag) {
  __shared__ ushort tile[64][65];
  int bf = flag[0];
  int k0 = blockIdx.y * 64, n0 = blockIdx.x * 64;
  int t = threadIdx.x;  // 256
#pragma unroll
  for (int i = 0; i < 16; ++i) {
    int idx = i * 256 + t;
    int r = idx >> 6, c = idx & 63;
    size_t g = (size_t)(k0 + r) * N + (n0 + c);
    tile[r][c] = bf ? ((const ushort*)in)[g] : f2b(((const float*)in)[g]);
  }
  __syncthreads();
#pragma unroll
  for (int i = 0; i < 16; ++i) {
    int idx = i * 256 + t;
    int r = idx >> 6, c = idx & 63;
    out[(size_t)(n0 + r) * K + (k0 + c)] = tile[c][r];
  }
}

// ---------------- MFMA GEMM: C[M,N] = A[M,K] @ BT[N,K]^T + bias ----------------
// A row stride = lda (elements). Register-prefetch pipeline (round 12).
#define BM 128
#define BN 128
#define BKK 32
#define LDA 40  // padded LDS row stride (elements); 80B, 16B-aligned (proven)

__global__ void gemm_bt(const void* __restrict__ A, const ushort* __restrict__ BT,
                        const void* __restrict__ bias, void* __restrict__ C,
                        int M, int N, int K, int lda, size_t a_off, size_t c_off,
                        const int* __restrict__ flag, int a_is_input, int c_is_output) {
  __shared__ __align__(16) ushort As[BM * LDA];
  __shared__ __align__(16) ushort Bs[BN * LDA];
  int bf = flag[0];
  int a_bf = a_is_input ? bf : 1;
  int tid = threadIdx.x;
  int wave = tid >> 6, lane = tid & 63;
  int lrow = lane & 15, quad = lane >> 4;
  int m0 = blockIdx.y * BM, n0 = blockIdx.x * BN;
  int wm = (wave >> 1) * 64, wn = (wave & 1) * 64;

  f32x4 acc[4][4] = {};

  const ushort* Bp = BT + (size_t)n0 * K;

  uint4 av[2], bv[2];
  // prologue: load tile kt=0 into registers
#pragma unroll
  for (int j = 0; j < 2; ++j) {
    int idx = j * 256 + tid;
    int r = idx >> 2;
    int c = (idx & 3) << 3;
    size_t ga = a_off + (size_t)(m0 + r) * lda + c;
    if (a_bf) {
      av[j] = *(const uint4*)((const ushort*)A + ga);
    } else {
      const float* Af = (const float*)A + ga;
      float4 f0 = *(const float4*)Af;
      float4 f1 = *(const float4*)(Af + 4);
      ushort tmp[8] = {f2b(f0.x), f2b(f0.y), f2b(f0.z), f2b(f0.w),
                       f2b(f1.x), f2b(f1.y), f2b(f1.z), f2b(f1.w)};
      av[j] = *(const uint4*)tmp;
    }
    bv[j] = *(const uint4*)(Bp + (size_t)r * K + c);
  }

  for (int kt = 0; kt < K; kt += BKK) {
    __syncthreads();  // previous iteration's LDS reads done
#pragma unroll
    for (int j = 0; j < 2; ++j) {
      int idx = j * 256 + tid;
      int r = idx >> 2;
      int c = (idx & 3) << 3;
      *(uint4*)&As[r * LDA + c] = av[j];
      *(uint4*)&Bs[r * LDA + c] = bv[j];
    }
    __syncthreads();

    // prefetch next tile (latency hides under ds_read + MFMA below)
    int ktn = kt + BKK;
    if (ktn < K) {
#pragma unroll
      for (int j = 0; j < 2; ++j) {
        int idx = j * 256 + tid;
        int r = idx >> 2;
        int c = (idx & 3) << 3;
        size_t ga = a_off + (size_t)(m0 + r) * lda + ktn + c;
        if (a_bf) {
          av[j] = *(const uint4*)((const ushort*)A + ga);
        } else {
          const float* Af = (const float*)A + ga;
          float4 f0 = *(const float4*)Af;
          float4 f1 = *(const float4*)(Af + 4);
          ushort tmp[8] = {f2b(f0.x), f2b(f0.y), f2b(f0.z), f2b(f0.w),
                           f2b(f1.x), f2b(f1.y), f2b(f1.z), f2b(f1.w)};
          av[j] = *(const uint4*)tmp;
        }
        bv[j] = *(const uint4*)(Bp + (size_t)r * K + ktn + c);
      }
    }

    bf16x8 af[4], bfr[4];
#pragma unroll
    for (int i = 0; i < 4; ++i) {
      af[i] = *(const bf16x8*)&As[(wm + i * 16 + lrow) * LDA + quad * 8];
      bfr[i] = *(const bf16x8*)&Bs[(wn + i * 16 + lrow) * LDA + quad * 8];
    }
#pragma unroll
    for (int i = 0; i < 4; ++i)
#pragma unroll
      for (int j = 0; j < 4; ++j)
        acc[i][j] = __builtin_amdgcn_mfma_f32_16x16x32_bf16(af[i], bfr[j], acc[i][j], 0, 0, 0);
  }

#pragma unroll
  for (int i = 0; i < 4; ++i) {
#pragma unroll
    for (int j = 0; j < 4; ++j) {
      int colg = n0 + wn + j * 16 + lrow;
      float bvs = bf ? b2f(((const ushort*)bias)[colg]) : ((const float*)bias)[colg];
#pragma unroll
      for (int r = 0; r < 4; ++r) {
        int rowg = m0 + wm + i * 16 + quad * 4 + r;
        float val = acc[i][j][r] + bvs;
        size_t ci = c_off + (size_t)rowg * N + colg;
        if (c_is_output && !bf)
          ((float*)C)[ci] = val;
        else
          ((ushort*)C)[ci] = f2b(val);
      }
    }
  }
}

// ---------------- MFMA causal flash attention (pair of batches) ----------------
// qkv [z][2048][3072] bf16: row = [Q 0..1023 | K 1024..2047 | V 2048..3071], head h at h*64.
// OUTPUT IS WRITTEN INTO THE Q REGION (cols h*64..h*64+63) — Q is consumed into registers
// at block start, and no block reads another block's Q rows/cols.
// grid (32, 16, 2): q-tile = 31 - blockIdx.x (heavy first), y = head, z = batch in pair.
#define LDK 72  // 144B row stride, 16B-aligned

__global__ void attn_mfma(ushort* __restrict__ qkv_all) {
  __shared__ __align__(16) ushort Ks[64 * LDK];   // [key][hd]
  __shared__ __align__(16) ushort Vs[64 * LDK];   // [hd][key] (transposed at stage)
  __shared__ __align__(16) ushort Ps[4][16 * LDK];

  ushort* qkv = qkv_all + (size_t)blockIdx.z * 2048 * 3072;
  int h = blockIdx.y;
  int qt = gridDim.x - 1 - blockIdx.x;  // heavy tiles dispatch first
  int q0 = qt * 64;
  int tid = threadIdx.x, wave = tid >> 6, lane = tid & 63;
  int lrow = lane & 15, quad = lane >> 4;

  // Q fragments for this wave's 16 rows: A[m=lrow][k=quad*8+j]
  bf16x8 qa[2];
#pragma unroll
  for (int kk = 0; kk < 2; ++kk)
    qa[kk] = *(const bf16x8*)(qkv + (size_t)(q0 + wave * 16 + lrow) * 3072 +
                              h * 64 + kk * 32 + quad * 8);

  f32x4 o[4] = {};
  float mi[4], li[4];
#pragma unroll
  for (int r = 0; r < 4; ++r) { mi[r] = -1e30f; li[r] = 0.f; }
  int row_g_base = q0 + wave * 16 + quad * 4;

  int ntiles = qt + 1;  // causal: keys [0, q0+64)

  // register prefetch of tile kt=0
  uint4 kv[2], vv[2];
#pragma unroll
  for (int j = 0; j < 2; ++j) {
    int idx = j * 256 + tid;
    {  // K rows
      int r = idx >> 3;
      int c = (idx & 7) << 3;
      kv[j] = *(const uint4*)(qkv + (size_t)r * 3072 + 1024 + h * 64 + c);
    }
    {  // V column gather (per-wave 128B-coalesced rows)
      int hd = idx & 63;
      int kb = idx >> 6;
      const ushort* vg = qkv + (size_t)(kb * 8) * 3072 + 2048 + h * 64 + hd;
      __align__(16) ushort col[8];
#pragma unroll
      for (int e = 0; e < 8; ++e) col[e] = vg[(size_t)e * 3072];
      vv[j] = *(const uint4*)col;
    }
  }

  for (int kt = 0; kt < ntiles; ++kt) {
    __syncthreads();  // previous iteration's Ks/Vs reads done
#pragma unroll
    for (int j = 0; j < 2; ++j) {
      int idx = j * 256 + tid;
      int r = idx >> 3;
      int c = (idx & 7) << 3;
      *(uint4*)&Ks[r * LDK + c] = kv[j];
      int hd = idx & 63;
      int kb = idx >> 6;
      *(uint4*)&Vs[hd * LDK + kb * 8] = vv[j];
    }
    __syncthreads();

    // prefetch next K/V tile (hides under QK^T/softmax/PV)
    if (kt + 1 < ntiles) {
#pragma unroll
      for (int j = 0; j < 2; ++j) {
        int idx = j * 256 + tid;
        {
          int r = idx >> 3;
          int c = (idx & 7) << 3;
          kv[j] = *(const uint4*)(qkv + (size_t)((kt + 1) * 64 + r) * 3072 + 1024 + h * 64 + c);
        }
        {
          int hd = idx & 63;
          int kb = idx >> 6;
          const ushort* vg = qkv + (size_t)((kt + 1) * 64 + kb * 8) * 3072 + 2048 + h * 64 + hd;
          __align__(16) ushort col[8];
#pragma unroll
          for (int e = 0; e < 8; ++e) col[e] = vg[(size_t)e * 3072];
          vv[j] = *(const uint4*)col;
        }
      }
    }

    // S = Q K^T (16 q-rows x 64 keys), C-layout (col=lrow=key, row=quad*4+r=q)
    f32x4 s4[4];
#pragma unroll
    for (int t = 0; t < 4; ++t) {
      f32x4 a = {};
#pragma unroll
      for (int kk = 0; kk < 2; ++kk) {
        bf16x8 kb = *(const bf16x8*)&Ks[(t * 16 + lrow) * LDK + kk * 32 + quad * 8];
        a = __builtin_amdgcn_mfma_f32_16x16x32_bf16(qa[kk], kb, a, 0, 0, 0);
      }
      s4[t] = a;
    }

    float tmax[4];
#pragma unroll
    for (int r = 0; r < 4; ++r) tmax[r] = -1e30f;
#pragma unroll
    for (int t = 0; t < 4; ++t) {
      int colg = kt * 64 + t * 16 + lrow;
#pragma unroll
      for (int r = 0; r < 4; ++r) {
        float v = s4[t][r] * 0.125f;
        if (colg > row_g_base + r) v = -1e30f;
        s4[t][r] = v;
        tmax[r] = fmaxf(tmax[r], v);
      }
    }
#pragma unroll
    for (int off = 8; off >= 1; off >>= 1)
#pragma unroll
      for (int r = 0; r < 4; ++r)
        tmax[r] = fmaxf(tmax[r], __shfl_xor(tmax[r], off, 64));

    float al[4], ps[4];
#pragma unroll
    for (int r = 0; r < 4; ++r) {
      float nm = fmaxf(mi[r], tmax[r]);
      al[r] = __expf(mi[r] - nm);
      mi[r] = nm;
      ps[r] = 0.f;
    }
#pragma unroll
    for (int t = 0; t < 4; ++t)
#pragma unroll
      for (int r = 0; r < 4; ++r) {
        float p = __expf(s4[t][r] - mi[r]);
        s4[t][r] = p;
        ps[r] += p;
      }
#pragma unroll
    for (int off = 8; off >= 1; off >>= 1)
#pragma unroll
      for (int r = 0; r < 4; ++r) ps[r] += __shfl_xor(ps[r], off, 64);
#pragma unroll
    for (int r = 0; r < 4; ++r) li[r] = li[r] * al[r] + ps[r];
#pragma unroll
    for (int t = 0; t < 4; ++t)
#pragma unroll
      for (int r = 0; r < 4; ++r) o[t][r] *= al[r];

    // P: C-layout -> LDS (wave-private) -> A-layout. No block barrier needed:
    // Ps[wave] is only touched by this wave; order via lgkmcnt + sched fence (rule 18).
#pragma unroll
    for (int t = 0; t < 4; ++t)
#pragma unroll
      for (int r = 0; r < 4; ++r)
        Ps[wave][(quad * 4 + r) * LDK + t * 16 + lrow] = f2b(s4[t][r]);

    asm volatile("s_waitcnt lgkmcnt(0)" ::: "memory");
    __builtin_amdgcn_sched_barrier(0);

    bf16x8 pa[2];
#pragma unroll
    for (int kk = 0; kk < 2; ++kk)
      pa[kk] = *(const bf16x8*)&Ps[wave][lrow * LDK + kk * 32 + quad * 8];
#pragma unroll
    for (int t = 0; t < 4; ++t)
#pragma unroll
      for (int kk = 0; kk < 2; ++kk) {
        bf16x8 vb = *(const bf16x8*)&Vs[(t * 16 + lrow) * LDK + kk * 32 + quad * 8];
        o[t] = __builtin_amdgcn_mfma_f32_16x16x32_bf16(pa[kk], vb, o[t], 0, 0, 0);
      }
  }

  // normalize + store INTO Q REGION: qkv[q][h*64 + t*16+lrow] (row stride 3072)
#pragma unroll
  for (int r = 0; r < 4; ++r) {
    float inv = 1.f / li[r];
    int q = q0 + wave * 16 + quad * 4 + r;
    size_t base = (size_t)q * 3072 + h * 64;
#pragma unroll
    for (int t = 0; t < 4; ++t) qkv[base + t * 16 + lrow] = f2b(o[t][r] * inv);
  }
}

static const void* ptr_by_size(void* const* d_in, const int* in_sizes, int n_in,
                               int want, int fallback_idx) {
  for (int i = 0; i < n_in; ++i)
    if (in_sizes[i] == want) return d_in[i];
  return d_in[fallback_idx];
}

extern "C" void kernel_launch(void* const* d_in, const int* in_sizes, int n_in,
                              void* d_out, int out_size, void* d_ws, size_t ws_size,
                              hipStream_t stream) {
  const void* x    = ptr_by_size(d_in, in_sizes, n_in, 8388608, 0);  // [4,2048,1024]
  const void* Wqkv = ptr_by_size(d_in, in_sizes, n_in, 3145728, 1);  // [1024,3072]
  const void* bqkv = ptr_by_size(d_in, in_sizes, n_in, 3072,    2);  // [3072]
  const void* Wout = ptr_by_size(d_in, in_sizes, n_in, 1048576, 3);  // [1024,1024]
  const void* bout = ptr_by_size(d_in, in_sizes, n_in, 1024,    4);  // [1024]

  char* ws = (char*)d_ws;
  int*    flag  = (int*)ws;                        // 256 B
  ushort* WT1   = (ushort*)(ws + 256);             // [3072][1024] bf16  6.29 MB
  ushort* WT2   = (ushort*)(ws + 256 + 6291456);   // [1024][1024] bf16  2.10 MB
  ushort* qkvb  = (ushort*)(ws + 256 + 8388608);   // [2][2048][3072] bf16 25.17 MB
  // total 33,554,688 B == largest previously observed PASSING ws

  detect_dtype<<<1, 1024, 0, stream>>>((const unsigned int*)x, flag);
  transpose_any<<<dim3(48, 16), 256, 0, stream>>>(Wqkv, WT1, 1024, 3072, flag);
  transpose_any<<<dim3(16, 16), 256, 0, stream>>>(Wout, WT2, 1024, 1024, flag);

  for (int p = 0; p < 2; ++p) {
    // QKV projection, 2 batches at once: [4096,1024] @ [1024,3072]
    gemm_bt<<<dim3(24, 32), 256, 0, stream>>>(
        x, WT1, bqkv, qkvb, 4096, 3072, 1024, /*lda=*/1024,
        (size_t)p * 4096 * 1024, 0, flag, /*a_is_input=*/1, /*c_is_output=*/0);
    // attention for both batches of the pair; output lands in Q region of qkvb
    attn_mfma<<<dim3(32, 16, 2), 256, 0, stream>>>(qkvb);
    // output projection, 2 batches at once: A = Q region of qkvb (lda=3072)
    gemm_bt<<<dim3(8, 32), 256, 0, stream>>>(
        qkvb, WT2, bout, d_out, 4096, 1024, 1024, /*lda=*/3072,
        0, (size_t)p * 4096 * 1024, flag, /*a_is_input=*/0, /*c_is_output=*/1);
  }
}

// Round 4
// 669.973 us; speedup vs baseline: 1.1691x; 1.1170x over previous
//
#include <hip/hip_runtime.h>
#include <hip/hip_bf16.h>

// B=4, S=2048, D=1024, H=16, HD=64. Inputs/output bf16 (flag=1 proven rounds 5+9+11+12).
// ws total 33,554,688 B (proven passing round 12).
// ROUND 14 DELTA vs round 13 (compile fail: __exp2f has no device overload):
//   exp2fast(): __builtin_amdgcn_exp2f if available (v_exp_f32 is natively 2^x),
//   else __expf(x*ln2). NOTHING else changed vs round 13:
//   attn_mfma with swapped QK^T (mfma(K,Q)): lane holds one q-row of S ->
//   in-lane softmax (2 shuffles), P->A-fragment via v_cvt_pk_bf16_f32 + shfl
//   register exchange (T12), Ps LDS buffer DELETED (LDS 27.6->18.4KB -> 3 blocks/CU).
// GEMMs unchanged (green).

typedef float f32x4 __attribute__((ext_vector_type(4)));
typedef short bf16x8 __attribute__((ext_vector_type(8)));

__device__ __forceinline__ ushort f2b(float f) {
  unsigned int x = __float_as_uint(f);
  unsigned int r = (x + 0x7fffu + ((x >> 16) & 1u)) >> 16;  // RNE
  return (ushort)r;
}
__device__ __forceinline__ float b2f(ushort u) {
  return __uint_as_float(((unsigned int)u) << 16);
}
__device__ __forceinline__ float exp2fast(float x) {
#if __has_builtin(__builtin_amdgcn_exp2f)
  return __builtin_amdgcn_exp2f(x);
#else
  return __expf(x * 0.69314718055994531f);
#endif
}

// ---------------- dtype detector (insurance; proven round 5/9) ----------------
__global__ void detect_dtype(const unsigned int* __restrict__ x, int* __restrict__ flag) {
  __shared__ int cnt;
  if (threadIdx.x == 0) cnt = 0;
  __syncthreads();
  unsigned int w = x[threadIdx.x];
  int e = (w >> 7) & 0xff;
  atomicAdd(&cnt, (e >= 96 && e <= 160) ? 1 : 0);
  __syncthreads();
  if (threadIdx.x == 0) flag[0] = (cnt >= 614) ? 1 : 0;
}

// ---------------- transpose: in (dtype per flag) [K][N] -> out bf16 [N][K] ----------------
__global__ void transpose_any(const void* __restrict__ in, ushort* __restrict__ out,
                              int K, int N, const int* __restrict__ flag) {
  __shared__ ushort tile[64][65];
  int bf = flag[0];
  int k0 = blockIdx.y * 64, n0 = blockIdx.x * 64;
  int t = threadIdx.x;  // 256
#pragma unroll
  for (int i = 0; i < 16; ++i) {
    int idx = i * 256 + t;
    int r = idx >> 6, c = idx & 63;
    size_t g = (size_t)(k0 + r) * N + (n0 + c);
    tile[r][c] = bf ? ((const ushort*)in)[g] : f2b(((const float*)in)[g]);
  }
  __syncthreads();
#pragma unroll
  for (int i = 0; i < 16; ++i) {
    int idx = i * 256 + t;
    int r = idx >> 6, c = idx & 63;
    out[(size_t)(n0 + r) * K + (k0 + c)] = tile[c][r];
  }
}

// ---------------- MFMA GEMM: C[M,N] = A[M,K] @ BT[N,K]^T + bias (round 12, green) ----------------
#define BM 128
#define BN 128
#define BKK 32
#define LDA 40  // padded LDS row stride (elements); 80B, 16B-aligned (proven)

__global__ void gemm_bt(const void* __restrict__ A, const ushort* __restrict__ BT,
                        const void* __restrict__ bias, void* __restrict__ C,
                        int M, int N, int K, int lda, size_t a_off, size_t c_off,
                        const int* __restrict__ flag, int a_is_input, int c_is_output) {
  __shared__ __align__(16) ushort As[BM * LDA];
  __shared__ __align__(16) ushort Bs[BN * LDA];
  int bf = flag[0];
  int a_bf = a_is_input ? bf : 1;
  int tid = threadIdx.x;
  int wave = tid >> 6, lane = tid & 63;
  int lrow = lane & 15, quad = lane >> 4;
  int m0 = blockIdx.y * BM, n0 = blockIdx.x * BN;
  int wm = (wave >> 1) * 64, wn = (wave & 1) * 64;

  f32x4 acc[4][4] = {};

  const ushort* Bp = BT + (size_t)n0 * K;

  uint4 av[2], bv[2];
  // prologue: load tile kt=0 into registers
#pragma unroll
  for (int j = 0; j < 2; ++j) {
    int idx = j * 256 + tid;
    int r = idx >> 2;
    int c = (idx & 3) << 3;
    size_t ga = a_off + (size_t)(m0 + r) * lda + c;
    if (a_bf) {
      av[j] = *(const uint4*)((const ushort*)A + ga);
    } else {
      const float* Af = (const float*)A + ga;
      float4 f0 = *(const float4*)Af;
      float4 f1 = *(const float4*)(Af + 4);
      ushort tmp[8] = {f2b(f0.x), f2b(f0.y), f2b(f0.z), f2b(f0.w),
                       f2b(f1.x), f2b(f1.y), f2b(f1.z), f2b(f1.w)};
      av[j] = *(const uint4*)tmp;
    }
    bv[j] = *(const uint4*)(Bp + (size_t)r * K + c);
  }

  for (int kt = 0; kt < K; kt += BKK) {
    __syncthreads();  // previous iteration's LDS reads done
#pragma unroll
    for (int j = 0; j < 2; ++j) {
      int idx = j * 256 + tid;
      int r = idx >> 2;
      int c = (idx & 3) << 3;
      *(uint4*)&As[r * LDA + c] = av[j];
      *(uint4*)&Bs[r * LDA + c] = bv[j];
    }
    __syncthreads();

    // prefetch next tile (latency hides under ds_read + MFMA below)
    int ktn = kt + BKK;
    if (ktn < K) {
#pragma unroll
      for (int j = 0; j < 2; ++j) {
        int idx = j * 256 + tid;
        int r = idx >> 2;
        int c = (idx & 3) << 3;
        size_t ga = a_off + (size_t)(m0 + r) * lda + ktn + c;
        if (a_bf) {
          av[j] = *(const uint4*)((const ushort*)A + ga);
        } else {
          const float* Af = (const float*)A + ga;
          float4 f0 = *(const float4*)Af;
          float4 f1 = *(const float4*)(Af + 4);
          ushort tmp[8] = {f2b(f0.x), f2b(f0.y), f2b(f0.z), f2b(f0.w),
                           f2b(f1.x), f2b(f1.y), f2b(f1.z), f2b(f1.w)};
          av[j] = *(const uint4*)tmp;
        }
        bv[j] = *(const uint4*)(Bp + (size_t)r * K + ktn + c);
      }
    }

    bf16x8 af[4], bfr[4];
#pragma unroll
    for (int i = 0; i < 4; ++i) {
      af[i] = *(const bf16x8*)&As[(wm + i * 16 + lrow) * LDA + quad * 8];
      bfr[i] = *(const bf16x8*)&Bs[(wn + i * 16 + lrow) * LDA + quad * 8];
    }
#pragma unroll
    for (int i = 0; i < 4; ++i)
#pragma unroll
      for (int j = 0; j < 4; ++j)
        acc[i][j] = __builtin_amdgcn_mfma_f32_16x16x32_bf16(af[i], bfr[j], acc[i][j], 0, 0, 0);
  }

#pragma unroll
  for (int i = 0; i < 4; ++i) {
#pragma unroll
    for (int j = 0; j < 4; ++j) {
      int colg = n0 + wn + j * 16 + lrow;
      float bvs = bf ? b2f(((const ushort*)bias)[colg]) : ((const float*)bias)[colg];
#pragma unroll
      for (int r = 0; r < 4; ++r) {
        int rowg = m0 + wm + i * 16 + quad * 4 + r;
        float val = acc[i][j][r] + bvs;
        size_t ci = c_off + (size_t)rowg * N + colg;
        if (c_is_output && !bf)
          ((float*)C)[ci] = val;
        else
          ((ushort*)C)[ci] = f2b(val);
      }
    }
  }
}

// ---------------- MFMA causal flash attention (pair of batches), swapped-QK^T ----------------
// qkv [z][2048][3072] bf16: row = [Q | K | V], head h at h*64. Output into Q region.
// grid (32, 16, 2): q-tile = 31 - blockIdx.x (heavy first), y = head, z = batch in pair.
// Swapped QK^T: s = mfma(K_frag, Q_frag) -> lane holds S[q=lrow][key=t*16+quad*4+r].
// Softmax in-lane (q per lane); P->A-fragment via cvt_pk_bf16 + shfl (no LDS round-trip).
#define LDK 72  // 144B row stride, 16B-aligned

__global__ void attn_mfma(ushort* __restrict__ qkv_all) {
  __shared__ __align__(16) ushort Ks[64 * LDK];   // [key][hd]
  __shared__ __align__(16) ushort Vs[64 * LDK];   // [hd][key] (transposed at stage)

  ushort* qkv = qkv_all + (size_t)blockIdx.z * 2048 * 3072;
  int h = blockIdx.y;
  int qt = gridDim.x - 1 - blockIdx.x;  // heavy tiles dispatch first
  int q0 = qt * 64;
  int tid = threadIdx.x, wave = tid >> 6, lane = tid & 63;
  int lrow = lane & 15, quad = lane >> 4;

  // Q fragments for this wave's 16 rows (rows indexed by lrow; used as B-operand now)
  bf16x8 qa[2];
#pragma unroll
  for (int kk = 0; kk < 2; ++kk)
    qa[kk] = *(const bf16x8*)(qkv + (size_t)(q0 + wave * 16 + lrow) * 3072 +
                              h * 64 + kk * 32 + quad * 8);

  f32x4 o[4] = {};                 // col=lrow=hd(t*16+lrow), row=quad*4+r=q
  float mi = -1e30f, li = 0.f;     // per-lane: q-row = lrow (base-2 domain)
  const float SCALE2 = 0.125f * 1.44269504089f;  // *log2(e): softmax in base-2
  int qg = q0 + wave * 16 + lrow;  // this lane's q row (for masking)

  int ntiles = qt + 1;  // causal: keys [0, q0+64)

  // register prefetch of tile kt=0
  uint4 kv[2], vv[2];
#pragma unroll
  for (int j = 0; j < 2; ++j) {
    int idx = j * 256 + tid;
    {  // K rows
      int r = idx >> 3;
      int c = (idx & 7) << 3;
      kv[j] = *(const uint4*)(qkv + (size_t)r * 3072 + 1024 + h * 64 + c);
    }
    {  // V column gather (per-wave 128B-coalesced rows)
      int hd = idx & 63;
      int kb = idx >> 6;
      const ushort* vg = qkv + (size_t)(kb * 8) * 3072 + 2048 + h * 64 + hd;
      __align__(16) ushort col[8];
#pragma unroll
      for (int e = 0; e < 8; ++e) col[e] = vg[(size_t)e * 3072];
      vv[j] = *(const uint4*)col;
    }
  }

  for (int kt = 0; kt < ntiles; ++kt) {
    __syncthreads();  // previous iteration's Ks/Vs reads done
#pragma unroll
    for (int j = 0; j < 2; ++j) {
      int idx = j * 256 + tid;
      int r = idx >> 3;
      int c = (idx & 7) << 3;
      *(uint4*)&Ks[r * LDK + c] = kv[j];
      int hd = idx & 63;
      int kb = idx >> 6;
      *(uint4*)&Vs[hd * LDK + kb * 8] = vv[j];
    }
    __syncthreads();

    // prefetch next K/V tile (hides under QK^T/softmax/PV)
    if (kt + 1 < ntiles) {
#pragma unroll
      for (int j = 0; j < 2; ++j) {
        int idx = j * 256 + tid;
        {
          int r = idx >> 3;
          int c = (idx & 7) << 3;
          kv[j] = *(const uint4*)(qkv + (size_t)((kt + 1) * 64 + r) * 3072 + 1024 + h * 64 + c);
        }
        {
          int hd = idx & 63;
          int kb = idx >> 6;
          const ushort* vg = qkv + (size_t)((kt + 1) * 64 + kb * 8) * 3072 + 2048 + h * 64 + hd;
          __align__(16) ushort col[8];
#pragma unroll
          for (int e = 0; e < 8; ++e) col[e] = vg[(size_t)e * 3072];
          vv[j] = *(const uint4*)col;
        }
      }
    }

    // S^T = K Q^T via mfma(K_frag, Q_frag): lane holds S[q=lrow][key=kt*64+t*16+quad*4+r]
    f32x4 s4[4];
#pragma unroll
    for (int t = 0; t < 4; ++t) {
      f32x4 a = {};
#pragma unroll
      for (int kk = 0; kk < 2; ++kk) {
        bf16x8 kb = *(const bf16x8*)&Ks[(t * 16 + lrow) * LDK + kk * 32 + quad * 8];
        a = __builtin_amdgcn_mfma_f32_16x16x32_bf16(kb, qa[kk], a, 0, 0, 0);
      }
      s4[t] = a;
    }

    // scale + causal mask + in-lane row max (this lane owns 16 of q-row's 64 keys)
    float tm = -1e30f;
#pragma unroll
    for (int t = 0; t < 4; ++t) {
      int keyb = kt * 64 + t * 16 + quad * 4;
#pragma unroll
      for (int r = 0; r < 4; ++r) {
        float v = s4[t][r] * SCALE2;
        if (keyb + r > qg) v = -1e30f;
        s4[t][r] = v;
        tm = fmaxf(tm, v);
      }
    }
    tm = fmaxf(tm, __shfl_xor(tm, 16, 64));
    tm = fmaxf(tm, __shfl_xor(tm, 32, 64));

    float nm = fmaxf(mi, tm);
    float al = exp2fast(mi - nm);
    mi = nm;
    float ps = 0.f;
#pragma unroll
    for (int t = 0; t < 4; ++t)
#pragma unroll
      for (int r = 0; r < 4; ++r) {
        float p = exp2fast(s4[t][r] - mi);
        s4[t][r] = p;
        ps += p;
      }
    ps += __shfl_xor(ps, 16, 64);
    ps += __shfl_xor(ps, 32, 64);
    li = li * al + ps;

    // redistribute al from per-lane (q=lrow) to C-layout rows (q=quad*4+r)
    int sbase = quad * 20;  // src lane = quad*16 + (quad*4+r)
    float alr[4];
#pragma unroll
    for (int r = 0; r < 4; ++r) alr[r] = __shfl(al, sbase + r, 64);
#pragma unroll
    for (int t = 0; t < 4; ++t)
#pragma unroll
      for (int r = 0; r < 4; ++r) o[t][r] *= alr[r];

    // pack P rows to bf16 pairs in-register: d[t][u] = keys t*16+quad*4+{2u,2u+1} of q=lrow
    unsigned d[4][2];
#pragma unroll
    for (int t = 0; t < 4; ++t) {
      asm("v_cvt_pk_bf16_f32 %0, %1, %2" : "=v"(d[t][0]) : "v"(s4[t][0]), "v"(s4[t][1]));
      asm("v_cvt_pk_bf16_f32 %0, %1, %2" : "=v"(d[t][1]) : "v"(s4[t][2]), "v"(s4[t][3]));
    }

    // exchange to A-fragment: lane (lrow=q, quad) needs keys kk*32 + quad*8 + 0..7
    //   = d[2kk + (quad>>1)][0..1] from src lanes ((quad&1)*2{,+1})*16 + lrow
    int srcA = ((quad & 1) << 5) | lrow;  // quad_s = (quad&1)*2
    int srcB = srcA + 16;                 // quad_s = (quad&1)*2 + 1
    bool thi = (quad & 2) != 0;
    bf16x8 pa[2];
#pragma unroll
    for (int kk = 0; kk < 2; ++kk) {
      unsigned a0 = d[2 * kk][0], a1 = d[2 * kk][1];
      unsigned b0 = d[2 * kk + 1][0], b1 = d[2 * kk + 1][1];
      unsigned xa0 = __shfl(a0, srcA, 64), xa1 = __shfl(a1, srcA, 64);
      unsigned xb0 = __shfl(b0, srcA, 64), xb1 = __shfl(b1, srcA, 64);
      unsigned ya0 = __shfl(a0, srcB, 64), ya1 = __shfl(a1, srcB, 64);
      unsigned yb0 = __shfl(b0, srcB, 64), yb1 = __shfl(b1, srcB, 64);
      __align__(16) unsigned w[4];
      w[0] = thi ? xb0 : xa0;
      w[1] = thi ? xb1 : xa1;
      w[2] = thi ? yb0 : ya0;
      w[3] = thi ? yb1 : ya1;
      pa[kk] = *(const bf16x8*)w;
    }

    // PV: o += P @ V (A = P rows, B^T rows = Vs[hd][key])
#pragma unroll
    for (int t = 0; t < 4; ++t)
#pragma unroll
      for (int kk = 0; kk < 2; ++kk) {
        bf16x8 vb = *(const bf16x8*)&Vs[(t * 16 + lrow) * LDK + kk * 32 + quad * 8];
        o[t] = __builtin_amdgcn_mfma_f32_16x16x32_bf16(pa[kk], vb, o[t], 0, 0, 0);
      }
  }

  // normalize + store INTO Q REGION: qkv[q][h*64 + t*16+lrow] (row stride 3072)
  int sbase = quad * 20;
  float lir[4];
#pragma unroll
  for (int r = 0; r < 4; ++r) lir[r] = __shfl(li, sbase + r, 64);
#pragma unroll
  for (int r = 0; r < 4; ++r) {
    float inv = 1.f / lir[r];
    int q = q0 + wave * 16 + quad * 4 + r;
    size_t base = (size_t)q * 3072 + h * 64;
#pragma unroll
    for (int t = 0; t < 4; ++t) qkv[base + t * 16 + lrow] = f2b(o[t][r] * inv);
  }
}

static const void* ptr_by_size(void* const* d_in, const int* in_sizes, int n_in,
                               int want, int fallback_idx) {
  for (int i = 0; i < n_in; ++i)
    if (in_sizes[i] == want) return d_in[i];
  return d_in[fallback_idx];
}

extern "C" void kernel_launch(void* const* d_in, const int* in_sizes, int n_in,
                              void* d_out, int out_size, void* d_ws, size_t ws_size,
                              hipStream_t stream) {
  const void* x    = ptr_by_size(d_in, in_sizes, n_in, 8388608, 0);  // [4,2048,1024]
  const void* Wqkv = ptr_by_size(d_in, in_sizes, n_in, 3145728, 1);  // [1024,3072]
  const void* bqkv = ptr_by_size(d_in, in_sizes, n_in, 3072,    2);  // [3072]
  const void* Wout = ptr_by_size(d_in, in_sizes, n_in, 1048576, 3);  // [1024,1024]
  const void* bout = ptr_by_size(d_in, in_sizes, n_in, 1024,    4);  // [1024]

  char* ws = (char*)d_ws;
  int*    flag  = (int*)ws;                        // 256 B
  ushort* WT1   = (ushort*)(ws + 256);             // [3072][1024] bf16  6.29 MB
  ushort* WT2   = (ushort*)(ws + 256 + 6291456);   // [1024][1024] bf16  2.10 MB
  ushort* qkvb  = (ushort*)(ws + 256 + 8388608);   // [2][2048][3072] bf16 25.17 MB
  // total 33,554,688 B (proven passing)

  detect_dtype<<<1, 1024, 0, stream>>>((const unsigned int*)x, flag);
  transpose_any<<<dim3(48, 16), 256, 0, stream>>>(Wqkv, WT1, 1024, 3072, flag);
  transpose_any<<<dim3(16, 16), 256, 0, stream>>>(Wout, WT2, 1024, 1024, flag);

  for (int p = 0; p < 2; ++p) {
    // QKV projection, 2 batches at once: [4096,1024] @ [1024,3072]
    gemm_bt<<<dim3(24, 32), 256, 0, stream>>>(
        x, WT1, bqkv, qkvb, 4096, 3072, 1024, /*lda=*/1024,
        (size_t)p * 4096 * 1024, 0, flag, /*a_is_input=*/1, /*c_is_output=*/0);
    // attention for both batches of the pair; output lands in Q region of qkvb
    attn_mfma<<<dim3(32, 16, 2), 256, 0, stream>>>(qkvb);
    // output projection, 2 batches at once: A = Q region of qkvb (lda=3072)
    gemm_bt<<<dim3(8, 32), 256, 0, stream>>>(
        qkvb, WT2, bout, d_out, 4096, 1024, 1024, /*lda=*/3072,
        0, (size_t)p * 4096 * 1024, flag, /*a_is_input=*/0, /*c_is_output=*/1);
  }
}